// Round 1
// baseline (721.126 us; speedup 1.0000x reference)
//
#include <hip/hip_runtime.h>
#include <cstdint>
#include <cstddef>

#define B_ 64
#define S_ 2048
#define H_ 512
#define R_ 256
#define M_ (B_ * S_)   // 131072
#define NEGV (-1.0e9f)

typedef short short8 __attribute__((ext_vector_type(8)));
typedef float f32x4 __attribute__((ext_vector_type(4)));
typedef unsigned short u16;

// ---------- helpers ----------
__device__ __forceinline__ u16 f2b(float x) {
    union { float f; uint32_t u; } c; c.f = x;
    uint32_t u = c.u;
    uint32_t r = (u + 0x7fffu + ((u >> 16) & 1u)) >> 16;   // RNE
    return (u16)r;
}
__device__ __forceinline__ float b2f(u16 u) {
    union { uint32_t u; float f; } c; c.u = ((uint32_t)u) << 16;
    return c.f;
}
__device__ __forceinline__ float fast_tanh(float v) {
    // tanh(v) = 1 - 2/(e^{2v}+1); exp overflow->inf->1, underflow->0->-1 (correct limits)
    float e = __expf(2.0f * v);
    return 1.0f - 2.0f / (e + 1.0f);
}
__device__ __forceinline__ void load_lds16(const void* g, void* l) {
    __builtin_amdgcn_global_load_lds((__attribute__((address_space(1))) void*)g,
                                     (__attribute__((address_space(3))) void*)l,
                                     16, 0, 0);
}

// ---------- K0: convert sent_h and Wh_w to bf16 ----------
__global__ void k_convert(const float* __restrict__ sent, const float* __restrict__ whw,
                          u16* __restrict__ sentb, u16* __restrict__ whwb) {
    const long n4_sent = (long)M_ * H_ / 4;           // 16777216
    const long n4_tot  = n4_sent + (long)H_ * H_ / 4; // +65536
    long stride = (long)gridDim.x * blockDim.x;
    for (long i = (long)blockIdx.x * blockDim.x + threadIdx.x; i < n4_tot; i += stride) {
        const float4* src; u16* dst; long j;
        if (i < n4_sent) { src = (const float4*)sent; dst = sentb; j = i; }
        else             { src = (const float4*)whw;  dst = whwb;  j = i - n4_sent; }
        float4 v = src[j];
        ushort4 o;
        o.x = f2b(v.x); o.y = f2b(v.y); o.z = f2b(v.z); o.w = f2b(v.w);
        *(ushort4*)(dst + 4 * j) = o;
    }
}

// ---------- K1: base[b,k] = rel@Wr^T + Wr_b + pool@Wg^T + Wg_b + Wh_b ----------
__global__ void k_base(const float* __restrict__ rel, const float* __restrict__ pool,
                       const float* __restrict__ Wg_w, const float* __restrict__ Wg_b,
                       const float* __restrict__ Wh_b,
                       const float* __restrict__ Wr_w, const float* __restrict__ Wr_b,
                       float* __restrict__ base) {
    int b = blockIdx.x;
    __shared__ __attribute__((aligned(16))) float srel[R_];
    __shared__ __attribute__((aligned(16))) float spool[H_];
    for (int i = threadIdx.x; i < R_; i += 256) srel[i]  = rel[b * R_ + i];
    for (int i = threadIdx.x; i < H_; i += 256) spool[i] = pool[b * H_ + i];
    __syncthreads();
    for (int k = threadIdx.x; k < H_; k += 256) {
        float acc = Wr_b[k] + Wg_b[k] + Wh_b[k];
        const float4* wr = (const float4*)(Wr_w + (size_t)k * R_);
        #pragma unroll 4
        for (int r4 = 0; r4 < R_ / 4; ++r4) {
            float4 w = wr[r4]; float4 x = ((const float4*)srel)[r4];
            acc += w.x * x.x + w.y * x.y + w.z * x.z + w.w * x.w;
        }
        const float4* wg = (const float4*)(Wg_w + (size_t)k * H_);
        #pragma unroll 4
        for (int h4 = 0; h4 < H_ / 4; ++h4) {
            float4 w = wg[h4]; float4 x = ((const float4*)spool)[h4];
            acc += w.x * x.x + w.y * x.y + w.z * x.z + w.w * x.w;
        }
        base[b * H_ + k] = acc;
    }
}

// ---------- K2: main GEMM [M,512]x[512,512]^T + tanh/alpha epilogue -> partial[4][M] ----------
// m97 structure: 128x128 tile, BK=64, 4 waves (2x2 of 64x64), 16x16x32 bf16 MFMA,
// global_load_lds width=16, LDS in 1KB "fragment chunks" (16 rows x 32 k) so both the
// async-load lane order and the ds_read_b128 fragment reads are contiguous/conflict-free.
__launch_bounds__(256)
__global__ void k_gemm(const u16* __restrict__ A,    // [M, 512] bf16
                       const u16* __restrict__ Bw,   // [512, 512] bf16 (Wh_w, B^T layout)
                       const float* __restrict__ base,  // [B_, H_]
                       const float* __restrict__ alpha, // [H_]
                       float* __restrict__ partial)     // [4][M]
{
    const int K = 512;
    int bid = blockIdx.x;
    int nb = bid & 3;
    int mb = bid >> 2;
    int m0 = mb * 128;
    int n0 = nb * 128;
    int b  = m0 >> 11;   // m0 / S_ ; S_=2048 divisible by 128 so one b per tile

    int tid = threadIdx.x;
    int w  = tid >> 6;      // wave 0..3
    int l  = tid & 63;
    int wm = w & 1, wn = w >> 1;
    int lr = l & 15;        // C col / frag row
    int lq = l >> 4;        // quad

    __shared__ u16 smA[128 * 64];   // 16 KB, chunked
    __shared__ u16 smB[128 * 64];   // 16 KB, chunked
    __shared__ float red[2][2][64];

    f32x4 zero = {0.f, 0.f, 0.f, 0.f};
    f32x4 acc[4][4];
    #pragma unroll
    for (int i = 0; i < 4; ++i)
        #pragma unroll
        for (int j = 0; j < 4; ++j) acc[i][j] = zero;

    for (int kt = 0; kt < 8; ++kt) {
        int k0 = kt * 64;
        // stage: each wave fills 4 A-chunks + 4 B-chunks (1 KB each)
        #pragma unroll
        for (int i = 0; i < 4; ++i) {
            int c  = w * 4 + i;
            int mf = c >> 1, kc = c & 1;
            int row = mf * 16 + lr;
            int col = k0 + kc * 32 + lq * 8;
            const u16* ga = A  + (size_t)(m0 + row) * K + col;
            const u16* gb = Bw + (size_t)(n0 + row) * K + col;
            load_lds16(ga, smA + c * 512);
            load_lds16(gb, smB + c * 512);
        }
        __syncthreads();   // drains vmcnt(0) then barrier
        #pragma unroll
        for (int kc = 0; kc < 2; ++kc) {
            short8 af[4], bf[4];
            #pragma unroll
            for (int mi = 0; mi < 4; ++mi)
                af[mi] = *(const short8*)(smA + ((wm * 4 + mi) * 2 + kc) * 512 + l * 8);
            #pragma unroll
            for (int ni = 0; ni < 4; ++ni)
                bf[ni] = *(const short8*)(smB + ((wn * 4 + ni) * 2 + kc) * 512 + l * 8);
            #pragma unroll
            for (int mi = 0; mi < 4; ++mi)
                #pragma unroll
                for (int ni = 0; ni < 4; ++ni)
                    acc[mi][ni] = __builtin_amdgcn_mfma_f32_16x16x32_bf16(af[mi], bf[ni], acc[mi][ni], 0, 0, 0);
        }
        __syncthreads();
    }

    // epilogue: logits partial = sum_n tanh(acc + base[b,n]) * alpha[n]
    // C layout (verified m89/m91): col = l&15, row = (l>>4)*4 + reg
    float basev[4], alphav[4];
    #pragma unroll
    for (int ni = 0; ni < 4; ++ni) {
        int n = n0 + wn * 64 + ni * 16 + lr;
        basev[ni]  = base[b * H_ + n];
        alphav[ni] = alpha[n];
    }
    #pragma unroll
    for (int mi = 0; mi < 4; ++mi) {
        #pragma unroll
        for (int r = 0; r < 4; ++r) {
            float s = 0.f;
            #pragma unroll
            for (int ni = 0; ni < 4; ++ni) {
                float v = acc[mi][ni][r] + basev[ni];
                s += fast_tanh(v) * alphav[ni];
            }
            // reduce over 16 cols (lanes sharing lq)
            s += __shfl_xor(s, 1);
            s += __shfl_xor(s, 2);
            s += __shfl_xor(s, 4);
            s += __shfl_xor(s, 8);
            if (lr == 0) red[wm][wn][mi * 16 + lq * 4 + r] = s;
        }
    }
    __syncthreads();
    if (tid < 128) {
        int wmi = tid >> 6, row = tid & 63;
        float sum = red[wmi][0][row] + red[wmi][1][row];
        partial[(size_t)nb * M_ + m0 + wmi * 64 + row] = sum;
    }
}

// ---------- K3: softmax over S per b ----------
__global__ void k_softmax(const float* __restrict__ partial, const int* __restrict__ mask,
                          const float* __restrict__ alpha_b, float* __restrict__ wout) {
    int b = blockIdx.x;
    int tid = threadIdx.x;
    __shared__ float sred[8];
    float x[8];
    float ab = alpha_b[0];
    float lmax = -3.0e38f;
    #pragma unroll
    for (int j = 0; j < 8; ++j) {
        int s = tid + j * 256;
        size_t m = (size_t)b * S_ + s;
        float v = partial[m] + partial[(size_t)M_ + m] + partial[2 * (size_t)M_ + m] + partial[3 * (size_t)M_ + m] + ab;
        if (mask[b * S_ + s] == 0) v = NEGV;
        x[j] = v;
        lmax = fmaxf(lmax, v);
    }
    #pragma unroll
    for (int off = 1; off < 64; off <<= 1) lmax = fmaxf(lmax, __shfl_xor(lmax, off));
    int wv = tid >> 6, l = tid & 63;
    if (l == 0) sred[wv] = lmax;
    __syncthreads();
    float gmax = fmaxf(fmaxf(sred[0], sred[1]), fmaxf(sred[2], sred[3]));
    float lsum = 0.f;
    #pragma unroll
    for (int j = 0; j < 8; ++j) { x[j] = __expf(x[j] - gmax); lsum += x[j]; }
    #pragma unroll
    for (int off = 1; off < 64; off <<= 1) lsum += __shfl_xor(lsum, off);
    if (l == 0) sred[4 + wv] = lsum;
    __syncthreads();
    float inv = 1.f / (sred[4] + sred[5] + sred[6] + sred[7]);
    #pragma unroll
    for (int j = 0; j < 8; ++j) {
        int s = tid + j * 256;
        wout[(size_t)b * S_ + s] = x[j] * inv;
    }
}

// ---------- K4: t[b,h'] = sum_s w[b,s] * sent_h_bf16[b,s,h'] ----------
__global__ void k_wsum(const u16* __restrict__ sentb, const float* __restrict__ wrow_g,
                       float* __restrict__ t) {
    int b  = blockIdx.x >> 2;
    int hc = blockIdx.x & 3;
    int tid = threadIdx.x;
    __shared__ float wrow[S_];
    __shared__ float4 red4[256];
    for (int i = tid; i < S_; i += 256) wrow[i] = wrow_g[(size_t)b * S_ + i];
    __syncthreads();
    int hi = tid & 31;   // 0..31 -> 4 h' each (128 per block)
    int sg = tid >> 5;   // 0..7
    int hb = hc * 128 + hi * 4;
    float a0 = 0.f, a1 = 0.f, a2 = 0.f, a3 = 0.f;
    const u16* basep = sentb + (size_t)b * S_ * H_ + hb;
    for (int s = sg; s < S_; s += 8) {
        ushort4 v = *(const ushort4*)(basep + (size_t)s * H_);
        float wgt = wrow[s];
        a0 += wgt * b2f(v.x); a1 += wgt * b2f(v.y); a2 += wgt * b2f(v.z); a3 += wgt * b2f(v.w);
    }
    red4[tid] = make_float4(a0, a1, a2, a3);
    __syncthreads();
    if (tid < 32) {
        float4 sacc = red4[tid];
        #pragma unroll
        for (int g = 1; g < 8; ++g) {
            float4 o = red4[g * 32 + tid];
            sacc.x += o.x; sacc.y += o.y; sacc.z += o.z; sacc.w += o.w;
        }
        float* tp = t + (size_t)b * H_ + hc * 128 + tid * 4;
        tp[0] = sacc.x; tp[1] = sacc.y; tp[2] = sacc.z; tp[3] = sacc.w;
    }
}

// ---------- K5: att_res[b,h] = Wh_b[h] + sum_h' t[b,h'] * Wh_w[h,h'] ----------
__global__ void k_att(const float* __restrict__ t, const float* __restrict__ Whw,
                      const float* __restrict__ Whb, float* __restrict__ out) {
    int b = blockIdx.x;
    int tid = threadIdx.x;
    __shared__ __attribute__((aligned(16))) float st[H_];
    for (int i = tid; i < H_; i += 256) st[i] = t[(size_t)b * H_ + i];
    __syncthreads();
    for (int h = tid; h < H_; h += 256) {
        const float4* wr = (const float4*)(Whw + (size_t)h * H_);
        float acc = 0.f;
        #pragma unroll 4
        for (int i4 = 0; i4 < H_ / 4; ++i4) {
            float4 w = wr[i4]; float4 x = ((const float4*)st)[i4];
            acc += w.x * x.x + w.y * x.y + w.z * x.z + w.w * x.w;
        }
        out[(size_t)b * H_ + h] = acc + Whb[h];
    }
}

extern "C" void kernel_launch(void* const* d_in, const int* in_sizes, int n_in,
                              void* d_out, int out_size, void* d_ws, size_t ws_size,
                              hipStream_t stream) {
    const float* sent_h  = (const float*)d_in[0];
    const float* rel     = (const float*)d_in[1];
    const float* pool    = (const float*)d_in[2];
    const int*   mask    = (const int*)d_in[3];
    const float* Wg_w    = (const float*)d_in[4];
    const float* Wg_b    = (const float*)d_in[5];
    const float* Wh_w    = (const float*)d_in[6];
    const float* Wh_b    = (const float*)d_in[7];
    const float* Wr_w    = (const float*)d_in[8];
    const float* Wr_b    = (const float*)d_in[9];
    const float* alpha_w = (const float*)d_in[10];
    const float* alpha_b = (const float*)d_in[11];
    float* out = (float*)d_out;

    // ws layout (137,101,312 bytes total)
    char* ws = (char*)d_ws;
    u16*   sentb   = (u16*)ws;                                   // 134217728 B
    u16*   whwb    = (u16*)(ws + 134217728);                     // 524288 B
    float* base    = (float*)(ws + 134217728 + 524288);          // 131072 B
    float* partial = (float*)(ws + 134217728 + 524288 + 131072); // 2097152 B
    float* tbuf    = (float*)(ws + 134217728 + 524288 + 131072 + 2097152); // 131072 B

    float* att_out = out;             // [64,512]
    float* w_out   = out + B_ * H_;   // [64,2048]

    k_convert<<<dim3(2048), dim3(256), 0, stream>>>(sent_h, Wh_w, sentb, whwb);
    k_base<<<dim3(B_), dim3(256), 0, stream>>>(rel, pool, Wg_w, Wg_b, Wh_b, Wr_w, Wr_b, base);
    k_gemm<<<dim3((M_ / 128) * 4), dim3(256), 0, stream>>>(sentb, whwb, base, alpha_w, partial);
    k_softmax<<<dim3(B_), dim3(256), 0, stream>>>(partial, mask, alpha_b, w_out);
    k_wsum<<<dim3(B_ * 4), dim3(256), 0, stream>>>(sentb, w_out, tbuf);
    k_att<<<dim3(B_), dim3(256), 0, stream>>>(tbuf, Wh_w, Wh_b, att_out);
}

// Round 2
// 614.739 us; speedup vs baseline: 1.1731x; 1.1731x over previous
//
#include <hip/hip_runtime.h>
#include <cstdint>
#include <cstddef>

#define B_ 64
#define S_ 2048
#define H_ 512
#define R_ 256
#define M_ (B_ * S_)   // 131072
#define NEGV (-1.0e9f)

typedef short short8 __attribute__((ext_vector_type(8)));
typedef unsigned short u16x8 __attribute__((ext_vector_type(8)));
typedef float f32x4 __attribute__((ext_vector_type(4)));
typedef unsigned short u16;

// ---------- helpers ----------
__device__ __forceinline__ u16 f2b(float x) {
    union { float f; uint32_t u; } c; c.f = x;
    uint32_t u = c.u;
    uint32_t r = (u + 0x7fffu + ((u >> 16) & 1u)) >> 16;   // RNE
    return (u16)r;
}
__device__ __forceinline__ float b2f(u16 u) {
    union { uint32_t u; float f; } c; c.u = ((uint32_t)u) << 16;
    return c.f;
}
__device__ __forceinline__ float fast_tanh(float v) {
    float e = __expf(2.0f * v);
    return 1.0f - 2.0f / (e + 1.0f);
}
__device__ __forceinline__ void load_lds16(const void* g, void* l) {
    __builtin_amdgcn_global_load_lds((__attribute__((address_space(1))) void*)g,
                                     (__attribute__((address_space(3))) void*)l,
                                     16, 0, 0);
}

// ---------- K0: convert sent_h to bf16 (pure stream: 32 B read, 16 B write per thread-iter) ----------
__global__ void k_convert(const float* __restrict__ sent, u16* __restrict__ sentb) {
    const long n8 = (long)M_ * H_ / 8;   // 8,388,608 groups of 8
    long stride = (long)gridDim.x * blockDim.x;
    for (long i = (long)blockIdx.x * blockDim.x + threadIdx.x; i < n8; i += stride) {
        float4 v0 = ((const float4*)sent)[2 * i];
        float4 v1 = ((const float4*)sent)[2 * i + 1];
        u16x8 o;
        o[0] = f2b(v0.x); o[1] = f2b(v0.y); o[2] = f2b(v0.z); o[3] = f2b(v0.w);
        o[4] = f2b(v1.x); o[5] = f2b(v1.y); o[6] = f2b(v1.z); o[7] = f2b(v1.w);
        ((u16x8*)sentb)[i] = o;
    }
}

// ---------- K1: base[b,k] = rel@Wr^T + Wr_b + pool@Wg^T + Wg_b + Wh_b  (+ Wh_w f32->bf16) ----------
// grid 256: b = blk>>2, quarter = blk&3 (128 outputs each); 2 half-waves split the 768-wide sum.
__global__ void k_base(const float* __restrict__ rel, const float* __restrict__ pool,
                       const float* __restrict__ Wg_w, const float* __restrict__ Wg_b,
                       const float* __restrict__ Wh_b,
                       const float* __restrict__ Wr_w, const float* __restrict__ Wr_b,
                       const float* __restrict__ whw, float* __restrict__ base,
                       u16* __restrict__ whwb) {
    int tid = threadIdx.x;
    {   // convert Wh_w: 262144 elems = 65536 float4 groups; exactly one per thread
        int gi = blockIdx.x * 256 + tid;
        float4 v = ((const float4*)whw)[gi];
        ushort4 o; o.x = f2b(v.x); o.y = f2b(v.y); o.z = f2b(v.z); o.w = f2b(v.w);
        ((ushort4*)whwb)[gi] = o;
    }
    int b = blockIdx.x >> 2, q = blockIdx.x & 3;
    __shared__ __attribute__((aligned(16))) float srel[R_];
    __shared__ __attribute__((aligned(16))) float spool[H_];
    __shared__ float accs[128];
    srel[tid & 255] = rel[b * R_ + (tid & 255)];
    for (int i = tid; i < H_; i += 256) spool[i] = pool[b * H_ + i];
    __syncthreads();
    int kk = tid & 127, half = tid >> 7;
    int k = q * 128 + kk;
    float acc = 0.f;
    if (half == 0) {
        acc = Wr_b[k] + Wg_b[k] + Wh_b[k];
        const float4* wr = (const float4*)(Wr_w + (size_t)k * R_);
        #pragma unroll 8
        for (int r4 = 0; r4 < R_ / 4; ++r4) {
            float4 w = wr[r4]; float4 x = ((const float4*)srel)[r4];
            acc += w.x * x.x + w.y * x.y + w.z * x.z + w.w * x.w;
        }
        const float4* wg = (const float4*)(Wg_w + (size_t)k * H_);
        #pragma unroll 8
        for (int h4 = 0; h4 < 32; ++h4) {
            float4 w = wg[h4]; float4 x = ((const float4*)spool)[h4];
            acc += w.x * x.x + w.y * x.y + w.z * x.z + w.w * x.w;
        }
    } else {
        const float4* wg = (const float4*)(Wg_w + (size_t)k * H_);
        #pragma unroll 8
        for (int h4 = 32; h4 < 128; ++h4) {
            float4 w = wg[h4]; float4 x = ((const float4*)spool)[h4];
            acc += w.x * x.x + w.y * x.y + w.z * x.z + w.w * x.w;
        }
    }
    if (half) accs[kk] = acc;
    __syncthreads();
    if (!half) base[b * H_ + k] = acc + accs[kk];
}

// ---------- K2: main GEMM [M,512]x[512,512]^T + tanh/alpha epilogue -> partial[4][M] ----------
// m97 structure + XCD swizzle: the 4 nb-blocks sharing an A-tile are spaced 8 apart in
// blockIdx so (with round-robin block->XCD dispatch) they run on the SAME XCD back-to-back
// and A is fetched from HBM once, then served from that XCD's L2.
__launch_bounds__(256)
__global__ void k_gemm(const u16* __restrict__ A,    // [M, 512] bf16
                       const u16* __restrict__ Bw,   // [512, 512] bf16 (Wh_w, B^T layout)
                       const float* __restrict__ base,  // [B_, H_]
                       const float* __restrict__ alpha, // [H_]
                       float* __restrict__ partial)     // [4][M]
{
    const int K = 512;
    int j = blockIdx.x;
    int xcd  = j & 7;
    int slot = j >> 3;
    int nb   = slot & 3;
    int mb   = (slot >> 2) * 8 + xcd;   // 0..1023, bijective over grid 4096
    int m0 = mb * 128;
    int n0 = nb * 128;
    int b  = m0 >> 11;   // m0 / S_

    int tid = threadIdx.x;
    int w  = tid >> 6;      // wave 0..3
    int l  = tid & 63;
    int wm = w & 1, wn = w >> 1;
    int lr = l & 15;        // C col / frag row
    int lq = l >> 4;        // quad

    __shared__ u16 smA[128 * 64];   // 16 KB, chunked
    __shared__ u16 smB[128 * 64];   // 16 KB, chunked
    __shared__ float red[2][2][64];

    f32x4 zero = {0.f, 0.f, 0.f, 0.f};
    f32x4 acc[4][4];
    #pragma unroll
    for (int i = 0; i < 4; ++i)
        #pragma unroll
        for (int jj = 0; jj < 4; ++jj) acc[i][jj] = zero;

    for (int kt = 0; kt < 8; ++kt) {
        int k0 = kt * 64;
        #pragma unroll
        for (int i = 0; i < 4; ++i) {
            int c  = w * 4 + i;
            int mf = c >> 1, kc = c & 1;
            int row = mf * 16 + lr;
            int col = k0 + kc * 32 + lq * 8;
            const u16* ga = A  + (size_t)(m0 + row) * K + col;
            const u16* gb = Bw + (size_t)(n0 + row) * K + col;
            load_lds16(ga, smA + c * 512);
            load_lds16(gb, smB + c * 512);
        }
        __syncthreads();
        #pragma unroll
        for (int kc = 0; kc < 2; ++kc) {
            short8 af[4], bf[4];
            #pragma unroll
            for (int mi = 0; mi < 4; ++mi)
                af[mi] = *(const short8*)(smA + ((wm * 4 + mi) * 2 + kc) * 512 + l * 8);
            #pragma unroll
            for (int ni = 0; ni < 4; ++ni)
                bf[ni] = *(const short8*)(smB + ((wn * 4 + ni) * 2 + kc) * 512 + l * 8);
            #pragma unroll
            for (int mi = 0; mi < 4; ++mi)
                #pragma unroll
                for (int ni = 0; ni < 4; ++ni)
                    acc[mi][ni] = __builtin_amdgcn_mfma_f32_16x16x32_bf16(af[mi], bf[ni], acc[mi][ni], 0, 0, 0);
        }
        __syncthreads();
    }

    // epilogue: partial logits = sum_n tanh(acc + base[b,n]) * alpha[n]
    float basev[4], alphav[4];
    #pragma unroll
    for (int ni = 0; ni < 4; ++ni) {
        int n = n0 + wn * 64 + ni * 16 + lr;
        basev[ni]  = base[b * H_ + n];
        alphav[ni] = alpha[n];
    }
    #pragma unroll
    for (int mi = 0; mi < 4; ++mi) {
        #pragma unroll
        for (int r = 0; r < 4; ++r) {
            float s = 0.f;
            #pragma unroll
            for (int ni = 0; ni < 4; ++ni) {
                float v = acc[mi][ni][r] + basev[ni];
                s += fast_tanh(v) * alphav[ni];
            }
            s += __shfl_xor(s, 1);
            s += __shfl_xor(s, 2);
            s += __shfl_xor(s, 4);
            s += __shfl_xor(s, 8);
            if (lr == 0) red[wm][wn][mi * 16 + lq * 4 + r] = s;
        }
    }
    __syncthreads();
    if (tid < 128) {
        int wmi = tid >> 6, row = tid & 63;
        float sum = red[wmi][0][row] + red[wmi][1][row];
        partial[(size_t)nb * M_ + m0 + wmi * 64 + row] = sum;
    }
}

// ---------- K3: softmax over S per b ----------
__global__ void k_softmax(const float* __restrict__ partial, const int* __restrict__ mask,
                          const float* __restrict__ alpha_b, float* __restrict__ wout) {
    int b = blockIdx.x;
    int tid = threadIdx.x;
    __shared__ float sred[8];
    float x[8];
    float ab = alpha_b[0];
    float lmax = -3.0e38f;
    #pragma unroll
    for (int jj = 0; jj < 8; ++jj) {
        int s = tid + jj * 256;
        size_t m = (size_t)b * S_ + s;
        float v = partial[m] + partial[(size_t)M_ + m] + partial[2 * (size_t)M_ + m] + partial[3 * (size_t)M_ + m] + ab;
        if (mask[b * S_ + s] == 0) v = NEGV;
        x[jj] = v;
        lmax = fmaxf(lmax, v);
    }
    #pragma unroll
    for (int off = 1; off < 64; off <<= 1) lmax = fmaxf(lmax, __shfl_xor(lmax, off));
    int wv = tid >> 6, l = tid & 63;
    if (l == 0) sred[wv] = lmax;
    __syncthreads();
    float gmax = fmaxf(fmaxf(sred[0], sred[1]), fmaxf(sred[2], sred[3]));
    float lsum = 0.f;
    #pragma unroll
    for (int jj = 0; jj < 8; ++jj) { x[jj] = __expf(x[jj] - gmax); lsum += x[jj]; }
    #pragma unroll
    for (int off = 1; off < 64; off <<= 1) lsum += __shfl_xor(lsum, off);
    if (l == 0) sred[4 + wv] = lsum;
    __syncthreads();
    float inv = 1.f / (sred[4] + sred[5] + sred[6] + sred[7]);
    #pragma unroll
    for (int jj = 0; jj < 8; ++jj) {
        int s = tid + jj * 256;
        wout[(size_t)b * S_ + s] = x[jj] * inv;
    }
}

// ---------- K4: t[b,h'] = sum_s w[b,s] * sent_h_bf16[b,s,h']  (grid B*8, 64 h' per block) ----------
__global__ void k_wsum(const u16* __restrict__ sentb, const float* __restrict__ wrow_g,
                       float* __restrict__ t) {
    int b  = blockIdx.x >> 3;
    int hc = blockIdx.x & 7;
    int tid = threadIdx.x;
    __shared__ __attribute__((aligned(16))) float wrow[S_];   // 8 KB
    __shared__ float4 red4[256];                              // 4 KB
    ((float4*)wrow)[tid]       = ((const float4*)(wrow_g + (size_t)b * S_))[tid];
    ((float4*)wrow)[tid + 256] = ((const float4*)(wrow_g + (size_t)b * S_))[tid + 256];
    __syncthreads();
    int hi = tid & 15, sg = tid >> 4;   // 16 s-groups
    const u16* bp = sentb + (size_t)b * S_ * H_ + hc * 64 + hi * 4;
    float a0 = 0.f, a1 = 0.f, a2 = 0.f, a3 = 0.f;
    for (int s0 = sg; s0 < S_; s0 += 64) {
        #pragma unroll
        for (int u = 0; u < 4; ++u) {       // 4 independent loads in flight
            int s = s0 + u * 16;
            ushort4 v = *(const ushort4*)(bp + (size_t)s * H_);
            float wgt = wrow[s];
            a0 += wgt * b2f(v.x); a1 += wgt * b2f(v.y); a2 += wgt * b2f(v.z); a3 += wgt * b2f(v.w);
        }
    }
    red4[tid] = make_float4(a0, a1, a2, a3);
    __syncthreads();
    if (tid < 16) {
        float4 sacc = red4[tid];
        #pragma unroll
        for (int g = 1; g < 16; ++g) {
            float4 o = red4[g * 16 + tid];
            sacc.x += o.x; sacc.y += o.y; sacc.z += o.z; sacc.w += o.w;
        }
        float* tp = t + (size_t)b * H_ + hc * 64 + tid * 4;
        tp[0] = sacc.x; tp[1] = sacc.y; tp[2] = sacc.z; tp[3] = sacc.w;
    }
}

// ---------- K5: att_res[b,h] = Wh_b[h] + sum_h' t[b,h'] * Wh_w[h,h']  (grid 256) ----------
__global__ void k_att(const float* __restrict__ t, const float* __restrict__ Whw,
                      const float* __restrict__ Whb, float* __restrict__ out) {
    int tid = threadIdx.x;
    int b = blockIdx.x >> 2, q = blockIdx.x & 3;
    __shared__ __attribute__((aligned(16))) float st[H_];
    __shared__ float accs[128];
    for (int i = tid; i < H_; i += 256) st[i] = t[(size_t)b * H_ + i];
    __syncthreads();
    int hh = tid & 127, half = tid >> 7;
    int h = q * 128 + hh;
    const float4* wr = (const float4*)(Whw + (size_t)h * H_) + half * 64;
    const float4* sx = (const float4*)st + half * 64;
    float acc = 0.f;
    #pragma unroll 8
    for (int i = 0; i < 64; ++i) {
        float4 w = wr[i]; float4 x = sx[i];
        acc += w.x * x.x + w.y * x.y + w.z * x.z + w.w * x.w;
    }
    if (half) accs[hh] = acc;
    __syncthreads();
    if (!half) out[(size_t)b * H_ + h] = acc + accs[hh] + Whb[h];
}

extern "C" void kernel_launch(void* const* d_in, const int* in_sizes, int n_in,
                              void* d_out, int out_size, void* d_ws, size_t ws_size,
                              hipStream_t stream) {
    const float* sent_h  = (const float*)d_in[0];
    const float* rel     = (const float*)d_in[1];
    const float* pool    = (const float*)d_in[2];
    const int*   mask    = (const int*)d_in[3];
    const float* Wg_w    = (const float*)d_in[4];
    const float* Wg_b    = (const float*)d_in[5];
    const float* Wh_w    = (const float*)d_in[6];
    const float* Wh_b    = (const float*)d_in[7];
    const float* Wr_w    = (const float*)d_in[8];
    const float* Wr_b    = (const float*)d_in[9];
    const float* alpha_w = (const float*)d_in[10];
    const float* alpha_b = (const float*)d_in[11];
    float* out = (float*)d_out;

    char* ws = (char*)d_ws;
    u16*   sentb   = (u16*)ws;                                   // 134217728 B
    u16*   whwb    = (u16*)(ws + 134217728);                     // 524288 B
    float* base    = (float*)(ws + 134217728 + 524288);          // 131072 B
    float* partial = (float*)(ws + 134217728 + 524288 + 131072); // 2097152 B
    float* tbuf    = (float*)(ws + 134217728 + 524288 + 131072 + 2097152); // 131072 B

    float* att_out = out;             // [64,512]
    float* w_out   = out + B_ * H_;   // [64,2048]

    k_convert<<<dim3(4096), dim3(256), 0, stream>>>(sent_h, sentb);
    k_base<<<dim3(256), dim3(256), 0, stream>>>(rel, pool, Wg_w, Wg_b, Wh_b, Wr_w, Wr_b, Wh_w, base, whwb);
    k_gemm<<<dim3((M_ / 128) * 4), dim3(256), 0, stream>>>(sentb, whwb, base, alpha_w, partial);
    k_softmax<<<dim3(B_), dim3(256), 0, stream>>>(partial, mask, alpha_b, w_out);
    k_wsum<<<dim3(B_ * 8), dim3(256), 0, stream>>>(sentb, w_out, tbuf);
    k_att<<<dim3(256), dim3(256), 0, stream>>>(tbuf, Wh_w, Wh_b, att_out);
}